// Round 2
// baseline (1175.711 us; speedup 1.0000x reference)
//
#include <hip/hip_runtime.h>
#include <hip/hip_bf16.h>

// Diffusion decoder, algebraically factored:
//   cond_b = MLP(pe[t_b]);  q_b = Wq@(qe_b+cond_b);  qk_b = Wk^T q_b
//   logit[b,v] = qk_b . te[b,v] + qk_b.cond_b + x[b,v]       (fp32 pass over te)
//   w = softmax(logit); s_b = sum_v w te[b,v]                (fp32 pass over te)
//   new_emb_b = Wp@(Wv@(s_b+cond_b)) + bp
//   A_b = Wd1[:, :512]@new_emb_b + bd1
//   p[b,v] = Wd2 . relu(A_b + Wd1[:,512:]@te[b,v]) + bd2 + w (bf16 MFMA GEMM, fused epilogue)
//
// Decoder v2: te-only LDS (64KB, fits default limit — v1's 96KB launch likely
// failed silently), W kept global in fragment-major order (L2-resident, each
// wave does 1KB coalesced loads), register double-buffer, no barriers in K-loop.

typedef __attribute__((ext_vector_type(8))) short bhalf8_t;   // 8 bf16 in 4 VGPRs
typedef __attribute__((ext_vector_type(4))) float fx4_t;

__device__ __forceinline__ unsigned short f2bf(float f) {
  unsigned int u = __float_as_uint(f);
  unsigned int r = (u + 0x7FFFu + ((u >> 16) & 1u)) >> 16;  // RNE
  return (unsigned short)r;
}

__device__ __forceinline__ float wave_sum64(float s) {
#pragma unroll
  for (int o = 32; o; o >>= 1) s += __shfl_xor(s, o, 64);
  return s;
}

// out[j] = act(bias[j] + dot(Wrow_j, v_lds[0:512])), 256 threads (4 waves), wave j-interleave.
template <int ACT>
__device__ __forceinline__ void mat_vec512(const float* __restrict__ W, int wstride,
                                           const float* __restrict__ bias,
                                           const float* v_lds, float* out_lds,
                                           float* __restrict__ out_g, int n, int tid) {
  const int wave = tid >> 6, lane = tid & 63;
  const float4* v4 = (const float4*)v_lds;
  float4 b0 = v4[lane], b1 = v4[lane + 64];
  for (int j = wave; j < n; j += 4) {
    const float4* wr = (const float4*)(W + (size_t)j * wstride);
    float4 a0 = wr[lane], a1 = wr[lane + 64];
    float s = a0.x * b0.x + a0.y * b0.y + a0.z * b0.z + a0.w * b0.w +
              a1.x * b1.x + a1.y * b1.y + a1.z * b1.z + a1.w * b1.w;
    s = wave_sum64(s);
    if (lane == 0) {
      if (bias) s += bias[j];
      if (ACT == 1) s = s / (1.f + expf(-s));  // silu
      if (out_lds) out_lds[j] = s;
      if (out_g) out_g[j] = s;
    }
  }
}

// ---------------- K1: per-batch prep (PE -> cond -> q -> qk, constb) ----------------
__global__ __launch_bounds__(256) void prep_kernel(
    const int* __restrict__ timesteps, const float* __restrict__ query_emb,
    const float* __restrict__ Wq, const float* __restrict__ Wk,
    const float* __restrict__ Wt1, const float* __restrict__ bt1,
    const float* __restrict__ Wt2, const float* __restrict__ bt2,
    float* __restrict__ cond_out, float* __restrict__ qk_out, float* __restrict__ constb_out) {
  __shared__ __attribute__((aligned(16))) float tv[512], hid[512], cond[512], q[512], qkv[512];
  __shared__ float red[4];
  const int b = blockIdx.x, tid = threadIdx.x;
  const int ts = timesteps[b];
  {
    const float NEG = -9.2103403719761836f / 512.f;  // -ln(10000)/512, exponent = 2*i
    float dv = expf((float)(2 * tid) * NEG);
    float ang = (float)ts * dv;
    tv[2 * tid] = sinf(ang);
    tv[2 * tid + 1] = cosf(ang);
  }
  __syncthreads();
  mat_vec512<1>(Wt1, 512, bt1, tv, hid, nullptr, 512, tid);
  __syncthreads();
  mat_vec512<0>(Wt2, 512, bt2, hid, cond, cond_out + (size_t)b * 512, 512, tid);
  __syncthreads();
  tv[tid] = query_emb[(size_t)b * 512 + tid] + cond[tid];
  tv[tid + 256] = query_emb[(size_t)b * 512 + tid + 256] + cond[tid + 256];
  __syncthreads();
  mat_vec512<0>(Wq, 512, nullptr, tv, q, nullptr, 512, tid);
  __syncthreads();
  // qk[e] = sum_d Wk[d][e] * q[d]   (column access -> coalesced over e)
  for (int e = tid; e < 512; e += 256) {
    float a = 0.f;
#pragma unroll 4
    for (int d = 0; d < 512; ++d) a += Wk[(size_t)d * 512 + e] * q[d];
    qkv[e] = a;
    qk_out[(size_t)b * 512 + e] = a;
  }
  __syncthreads();
  float c = qkv[tid] * cond[tid] + qkv[tid + 256] * cond[tid + 256];
  c = wave_sum64(c);
  if ((tid & 63) == 0) red[tid >> 6] = c;
  __syncthreads();
  if (tid == 0) constb_out[b] = red[0] + red[1] + red[2] + red[3];
}

// ---------------- K2: Wd1[:,512:] -> bf16 in fragment-major order ----------------
// wsW byte addr = ((((nc*8 + ks)*8 + nh*2+n)*2 + kc)*64 + lane)*16
// holding W[j][k..k+7] with j = nc*128 + (nh)*32 + n*16 + (lane&15),
//                         k = ks*64 + kc*32 + (lane>>4)*8.
__global__ __launch_bounds__(256) void convw_kernel(const float* __restrict__ Wd1,
                                                    unsigned short* __restrict__ wsW) {
  const int g = blockIdx.x * 256 + threadIdx.x;  // 0..65535
  const int lane = g & 63;
  const int kc = (g >> 6) & 1;
  const int nhn = (g >> 7) & 7;
  const int ks = (g >> 10) & 7;
  const int nc = g >> 13;
  const int j = nc * 128 + (nhn >> 1) * 32 + (nhn & 1) * 16 + (lane & 15);
  const int k = ks * 64 + kc * 32 + (lane >> 4) * 8;
  const float* src = Wd1 + (size_t)j * 1024 + 512 + k;
  float4 f0 = *(const float4*)src;
  float4 f1 = *(const float4*)(src + 4);
  ushort4 h0 = make_ushort4(f2bf(f0.x), f2bf(f0.y), f2bf(f0.z), f2bf(f0.w));
  ushort4 h1 = make_ushort4(f2bf(f1.x), f2bf(f1.y), f2bf(f1.z), f2bf(f1.w));
  ushort4* dst = (ushort4*)((char*)wsW + (size_t)g * 16);
  dst[0] = h0;
  dst[1] = h1;
}

// ---------------- K3: logits (fp32 dot pass over te) ----------------
__global__ __launch_bounds__(256) void logits_kernel(
    const float* __restrict__ te, const float* __restrict__ qk,
    const float* __restrict__ constb, const float* __restrict__ x, float* __restrict__ logits) {
  const int wave = threadIdx.x >> 6, lane = threadIdx.x & 63;
  const size_t r = (size_t)blockIdx.x * 4 + wave;
  const int b = (int)(r >> 10);
  const float4* t4 = (const float4*)(te + r * 512);
  const float4* q4 = (const float4*)(qk + (size_t)b * 512);
  float4 a0 = t4[lane], a1 = t4[lane + 64];
  float4 c0 = q4[lane], c1 = q4[lane + 64];
  float s = a0.x * c0.x + a0.y * c0.y + a0.z * c0.z + a0.w * c0.w +
            a1.x * c1.x + a1.y * c1.y + a1.z * c1.z + a1.w * c1.w;
  s = wave_sum64(s);
  if (lane == 0) logits[r] = s + constb[b] + x[r];
}

// ---------------- K4: softmax per batch; also init out = w + bd2 ----------------
__global__ __launch_bounds__(256) void softmax_kernel(
    const float* __restrict__ logits, const float* __restrict__ bd2,
    float* __restrict__ weight, float* __restrict__ out) {
  __shared__ float sm[4];
  const int b = blockIdx.x, tid = threadIdx.x;
  const int wave = tid >> 6, lane = tid & 63;
  float4 l4 = ((const float4*)(logits + (size_t)b * 1024))[tid];
  float m = fmaxf(fmaxf(l4.x, l4.y), fmaxf(l4.z, l4.w));
#pragma unroll
  for (int o = 32; o; o >>= 1) m = fmaxf(m, __shfl_xor(m, o, 64));
  if (lane == 0) sm[wave] = m;
  __syncthreads();
  float M = fmaxf(fmaxf(sm[0], sm[1]), fmaxf(sm[2], sm[3]));
  __syncthreads();
  float e0 = expf(l4.x - M), e1 = expf(l4.y - M), e2 = expf(l4.z - M), e3 = expf(l4.w - M);
  float ssum = wave_sum64(e0 + e1 + e2 + e3);
  if (lane == 0) sm[wave] = ssum;
  __syncthreads();
  float inv = 1.f / (sm[0] + sm[1] + sm[2] + sm[3]);
  float c = bd2[0];
  float4 w4 = make_float4(e0 * inv, e1 * inv, e2 * inv, e3 * inv);
  ((float4*)(weight + (size_t)b * 1024))[tid] = w4;
  ((float4*)(out + (size_t)b * 1024))[tid] = make_float4(w4.x + c, w4.y + c, w4.z + c, w4.w + c);
}

// ---------------- K5a: s_b = sum_v w * te  (fp32 pass over te, partial per v-chunk) ----------------
__global__ __launch_bounds__(256) void wsum_kernel(const float* __restrict__ te,
                                                   const float* __restrict__ weight,
                                                   float* __restrict__ s) {
  __shared__ float wl[128];
  const int b = blockIdx.x >> 3, vq = blockIdx.x & 7;
  const int tid = threadIdx.x;
  if (tid < 128) wl[tid] = weight[(size_t)b * 1024 + vq * 128 + tid];
  __syncthreads();
  const float* tb = te + ((size_t)b * 1024 + (size_t)vq * 128) * 512;
  float s0 = 0.f, s1 = 0.f;
#pragma unroll 4
  for (int v = 0; v < 128; ++v) {
    float w = wl[v];
    s0 += w * tb[(size_t)v * 512 + tid];
    s1 += w * tb[(size_t)v * 512 + 256 + tid];
  }
  atomicAdd(&s[(size_t)b * 512 + tid], s0);
  atomicAdd(&s[(size_t)b * 512 + 256 + tid], s1);
}

// ---------------- K5b: per-batch chains -> A_b ----------------
__global__ __launch_bounds__(256) void batch2_kernel(
    const float* __restrict__ s, const float* __restrict__ cond, const float* __restrict__ Wv,
    const float* __restrict__ Wp, const float* __restrict__ bp, const float* __restrict__ Wd1,
    const float* __restrict__ bd1, float* __restrict__ A) {
  __shared__ __attribute__((aligned(16))) float sc[512], u[512], ne[512];
  const int b = blockIdx.x, tid = threadIdx.x;
  sc[tid] = s[(size_t)b * 512 + tid] + cond[(size_t)b * 512 + tid];
  sc[tid + 256] = s[(size_t)b * 512 + tid + 256] + cond[(size_t)b * 512 + tid + 256];
  __syncthreads();
  mat_vec512<0>(Wv, 512, nullptr, sc, u, nullptr, 512, tid);
  __syncthreads();
  mat_vec512<0>(Wp, 512, bp, u, ne, nullptr, 512, tid);
  __syncthreads();
  mat_vec512<0>(Wd1, 1024, bd1, ne, nullptr, A + (size_t)b * 1024, 1024, tid);
}

// ---------------- K6: decoder GEMM + fused epilogue ----------------
// 2048 blocks x 512 thr (8 waves: 2M x 4N). Block: 64 te-rows x N=1024, K=512.
// LDS: te [64 rows][512 bf16] XOR-swizzled = 64 KiB only.
// W: global fragment-major (L2-resident), register double-buffered; no K-loop barriers.
__global__ __launch_bounds__(512) void decoder_kernel(
    const float* __restrict__ te, const unsigned short* __restrict__ wsW,
    const float* __restrict__ A, const float* __restrict__ Wd2, float* __restrict__ out) {
  extern __shared__ char te_lds[];  // 65536 B

  const int tid = threadIdx.x;
  const int wave = tid >> 6, lane = tid & 63;
  const int lhi = lane >> 4, llo = lane & 15;
  const int mh = wave >> 2, nh = wave & 3;  // wave tile: rows mh*32+[0,32), col-group nh
  const size_t row0 = (size_t)blockIdx.x * 64;
  const int b = (int)(blockIdx.x >> 4);

  // stage te tile: 64 rows x 512 f32 -> bf16 LDS, byte ^= (row&7)<<4 swizzle
  {
    const float4* te4 = (const float4*)(te + row0 * 512);
#pragma unroll
    for (int it = 0; it < 16; ++it) {
      int f = it * 512 + tid;
      int r = f >> 7, c4 = f & 127;
      float4 v = te4[f];
      ushort4 h = make_ushort4(f2bf(v.x), f2bf(v.y), f2bf(v.z), f2bf(v.w));
      *(ushort4*)(te_lds + r * 1024 + ((c4 * 8) ^ ((r & 7) << 4))) = h;
    }
  }
  __syncthreads();

  // A-fragment LDS byte offsets (row = lane&15 within 16-row tile, k = (lane>>4)*8 + i)
  int aoff[2][2];
#pragma unroll
  for (int m = 0; m < 2; ++m)
#pragma unroll
    for (int kc = 0; kc < 2; ++kc) {
      int r = mh * 32 + m * 16 + llo;
      aoff[m][kc] = r * 1024 + ((kc * 64 + lhi * 16) ^ ((r & 7) << 4));
    }

  // W fragment base: iter c -> wbase + c*16384 + n*2048 + kc*1024 (1KB coalesced per frag)
  const char* wbase = (const char*)wsW + nh * 4096 + lane * 16;
  const float* A_g = A + (size_t)b * 1024;

  float pacc[2][4] = {};
  fx4_t acc[2][2];
  const fx4_t zf = {0.f, 0.f, 0.f, 0.f};
  bhalf8_t bwA[2][2], bwB[2][2];

  auto loadw = [&](bhalf8_t (&dst)[2][2], int c) {
    const char* p = wbase + (size_t)c * 16384;
#pragma unroll
    for (int n = 0; n < 2; ++n)
#pragma unroll
      for (int kc = 0; kc < 2; ++kc)
        dst[n][kc] = *(const bhalf8_t*)(p + n * 2048 + kc * 1024);
  };

  auto body = [&](bhalf8_t (&bw)[2][2], int c) {
    const int nc = c >> 3, ks = c & 7;
    if (ks == 0) {
      acc[0][0] = zf; acc[0][1] = zf; acc[1][0] = zf; acc[1][1] = zf;
    }
    const char* tb = te_lds + ks * 128;
#pragma unroll
    for (int kc = 0; kc < 2; ++kc) {
      bhalf8_t a0 = *(const bhalf8_t*)(tb + aoff[0][kc]);
      bhalf8_t a1 = *(const bhalf8_t*)(tb + aoff[1][kc]);
      acc[0][0] = __builtin_amdgcn_mfma_f32_16x16x32_bf16(a0, bw[0][kc], acc[0][0], 0, 0, 0);
      acc[0][1] = __builtin_amdgcn_mfma_f32_16x16x32_bf16(a0, bw[1][kc], acc[0][1], 0, 0, 0);
      acc[1][0] = __builtin_amdgcn_mfma_f32_16x16x32_bf16(a1, bw[0][kc], acc[1][0], 0, 0, 0);
      acc[1][1] = __builtin_amdgcn_mfma_f32_16x16x32_bf16(a1, bw[1][kc], acc[1][1], 0, 0, 0);
    }
    if (ks == 7) {  // epilogue for this 128-col chunk (registers only)
      const int jb = nc * 128 + nh * 32;
#pragma unroll
      for (int n = 0; n < 2; ++n) {
        const int j = jb + n * 16 + llo;
        const float av = A_g[j];
        const float wv = Wd2[j];
#pragma unroll
        for (int m = 0; m < 2; ++m)
#pragma unroll
          for (int rg = 0; rg < 4; ++rg)
            pacc[m][rg] += fmaxf(acc[m][n][rg] + av, 0.f) * wv;
      }
    }
  };

  loadw(bwA, 0);
  for (int cp = 0; cp < 32; ++cp) {
    loadw(bwB, cp * 2 + 1);
    body(bwA, cp * 2);
    if (cp < 31) loadw(bwA, cp * 2 + 2);
    body(bwB, cp * 2 + 1);
  }

  // block-level reduction: sum the 4 nh-waves' partial row sums via LDS (te_lds is dead)
  __syncthreads();
  float* red = (float*)te_lds;  // [4 nh][64 rows]
#pragma unroll
  for (int m = 0; m < 2; ++m)
#pragma unroll
    for (int rg = 0; rg < 4; ++rg) {
      float sv = pacc[m][rg];
      sv += __shfl_xor(sv, 1, 64);
      sv += __shfl_xor(sv, 2, 64);
      sv += __shfl_xor(sv, 4, 64);
      sv += __shfl_xor(sv, 8, 64);
      if (llo == 0) red[nh * 64 + mh * 32 + m * 16 + lhi * 4 + rg] = sv;
    }
  __syncthreads();
  if (tid < 64) {
    float s = red[tid] + red[64 + tid] + red[128 + tid] + red[192 + tid];
    out[row0 + tid] += s;  // out pre-initialized to w + bd2; rows exclusive to this block
  }
}

// ---------------- launch ----------------
extern "C" void kernel_launch(void* const* d_in, const int* in_sizes, int n_in,
                              void* d_out, int out_size, void* d_ws, size_t ws_size,
                              hipStream_t stream) {
  const float* x = (const float*)d_in[0];
  const int* tsteps = (const int*)d_in[1];
  const float* qe = (const float*)d_in[2];
  const float* te = (const float*)d_in[3];
  const float* Wq = (const float*)d_in[4];
  const float* Wk = (const float*)d_in[5];
  const float* Wv = (const float*)d_in[6];
  const float* Wp = (const float*)d_in[7];
  const float* bp = (const float*)d_in[8];
  const float* Wt1 = (const float*)d_in[9];
  const float* bt1 = (const float*)d_in[10];
  const float* Wt2 = (const float*)d_in[11];
  const float* bt2 = (const float*)d_in[12];
  const float* Wd1 = (const float*)d_in[13];
  const float* bd1 = (const float*)d_in[14];
  const float* Wd2 = (const float*)d_in[15];
  const float* bd2 = (const float*)d_in[16];
  float* out = (float*)d_out;

  char* ws = (char*)d_ws;
  unsigned short* wsW = (unsigned short*)(ws + 0);   // 1,048,576 B
  float* cond = (float*)(ws + 1048576);              // 262,144
  float* qk = (float*)(ws + 1310720);                // 262,144
  float* cb = (float*)(ws + 1572864);                // 512
  float* logits = (float*)(ws + 1573376);            // 524,288
  float* wgt = (float*)(ws + 2097664);               // 524,288
  float* sbuf = (float*)(ws + 2621952);              // 262,144
  float* Abuf = (float*)(ws + 2884096);              // 524,288  -> total ~3.3 MB

  prep_kernel<<<128, 256, 0, stream>>>(tsteps, qe, Wq, Wk, Wt1, bt1, Wt2, bt2, cond, qk, cb);
  convw_kernel<<<256, 256, 0, stream>>>(Wd1, wsW);
  logits_kernel<<<32768, 256, 0, stream>>>(te, qk, cb, x, logits);
  softmax_kernel<<<128, 256, 0, stream>>>(logits, bd2, wgt, out);
  hipMemsetAsync(sbuf, 0, 128 * 512 * 4, stream);
  wsum_kernel<<<1024, 256, 0, stream>>>(te, wgt, sbuf);
  batch2_kernel<<<128, 256, 0, stream>>>(sbuf, cond, Wv, Wp, bp, Wd1, bd1, Abuf);

  (void)hipFuncSetAttribute((const void*)decoder_kernel,
                            hipFuncAttributeMaxDynamicSharedMemorySize, 65536);
  decoder_kernel<<<2048, 512, 65536, stream>>>(te, wsW, Abuf, Wd2, out);
}

// Round 3
// 515.139 us; speedup vs baseline: 2.2823x; 2.2823x over previous
//
#include <hip/hip_runtime.h>
#include <hip/hip_bf16.h>

// Diffusion decoder, algebraically factored:
//   cond_b = MLP(pe[t_b]);  q_b = Wq@(qe_b+cond_b);  qk_b = q_b @ Wk
//   logit[b,v] = qk_b . te[b,v] + qk_b.cond_b + x[b,v]       (fp32 pass over te)
//   w = softmax(logit); s_b = sum_v w te[b,v]                (bf16 pass over te)
//   new_emb_b = Wp@(Wv@(s_b+cond_b)) + bp
//   A_b = Wd1[:, :512]@new_emb_b + bd1
//   p[b,v] = Wd2 . relu(A_b + Wd1[:,512:]@te[b,v]) + bd2 + w (bf16 MFMA GEMM, fused epilogue)
//
// v3: prep/batch2 serial matvec chains (386 µs + ~280 µs, VALUBusy 2.7%) replaced
// by transposed-weight batched mat-vec kernels (~5 µs each). te cached as bf16 by
// the logits pass (ws_size permitting) so wsum + decoder fetch 134 MB, not 268.

typedef __attribute__((ext_vector_type(8))) short bhalf8_t;   // 8 bf16 in 4 VGPRs
typedef __attribute__((ext_vector_type(8))) unsigned short ushort8_t;
typedef __attribute__((ext_vector_type(4))) float fx4_t;

__device__ __forceinline__ unsigned short f2bf(float f) {
  unsigned int u = __float_as_uint(f);
  unsigned int r = (u + 0x7FFFu + ((u >> 16) & 1u)) >> 16;  // RNE
  return (unsigned short)r;
}
__device__ __forceinline__ float bf2f(unsigned short h) {
  return __uint_as_float((unsigned int)h << 16);
}

__device__ __forceinline__ float wave_sum64(float s) {
#pragma unroll
  for (int o = 32; o; o >>= 1) s += __shfl_xor(s, o, 64);
  return s;
}

// ---------------- T: transpose src[rows][0:512] (row stride srcStride) -> dst[512][rows] ----------------
__global__ __launch_bounds__(256) void transpose_kernel(const float* __restrict__ src,
                                                        float* __restrict__ dst,
                                                        int rows, int srcStride) {
  __shared__ float t[32][33];
  const int tx = threadIdx.x & 31, ty = threadIdx.x >> 5;
  const int c0 = blockIdx.x * 32, r0 = blockIdx.y * 32;
#pragma unroll
  for (int i = 0; i < 32; i += 8)
    t[ty + i][tx] = src[(size_t)(r0 + ty + i) * srcStride + c0 + tx];
  __syncthreads();
#pragma unroll
  for (int i = 0; i < 32; i += 8)
    dst[(size_t)(c0 + ty + i) * rows + r0 + tx] = t[tx][ty + i];
}

// ---------------- G: batched mat-vec  out[b][j] = act(bias[j] + sum_k arow[b][k] * WT[k][j]) ----------------
// MODE: 0 = arow from sinusoidal PE of timesteps[b]; 1 = src1[b]; 2 = src1[b]+src2[b];
//       3 = src2[b] + sum_{q<8} src1[(b*8+q)*512]   (wsum partials + cond)
// ACT:  0 none, 1 silu
template <int MODE, int ACT>
__global__ __launch_bounds__(256) void gvec_kernel(
    const float* __restrict__ WT, int n, const float* __restrict__ src1,
    const float* __restrict__ src2, const float* __restrict__ bias,
    const int* __restrict__ timesteps, float* __restrict__ outp) {
  __shared__ __attribute__((aligned(16))) float arow[512];
  const int b = blockIdx.x, tid = threadIdx.x;
  if (MODE == 0) {
    const int ts = timesteps[b];
    const float NEG = -9.2103403719761836f / 512.f;  // -ln(10000)/512
    float dv = expf((float)(2 * tid) * NEG);
    float ang = (float)ts * dv;
    arow[2 * tid] = sinf(ang);
    arow[2 * tid + 1] = cosf(ang);
  } else {
#pragma unroll
    for (int k = tid; k < 512; k += 256) {
      float a;
      if (MODE == 1) {
        a = src1[(size_t)b * 512 + k];
      } else if (MODE == 2) {
        a = src1[(size_t)b * 512 + k] + src2[(size_t)b * 512 + k];
      } else {
        a = src2[(size_t)b * 512 + k];
#pragma unroll
        for (int q = 0; q < 8; ++q) a += src1[((size_t)b * 8 + q) * 512 + k];
      }
      arow[k] = a;
    }
  }
  __syncthreads();
  const int j = blockIdx.y * 256 + tid;
  const float* w = WT + j;
  float s0 = 0.f, s1 = 0.f, s2 = 0.f, s3 = 0.f;
#pragma unroll 4
  for (int k = 0; k < 512; k += 4) {
    s0 = fmaf(arow[k], w[(size_t)k * n], s0);
    s1 = fmaf(arow[k + 1], w[(size_t)(k + 1) * n], s1);
    s2 = fmaf(arow[k + 2], w[(size_t)(k + 2) * n], s2);
    s3 = fmaf(arow[k + 3], w[(size_t)(k + 3) * n], s3);
  }
  float s = (s0 + s1) + (s2 + s3);
  if (bias) s += bias[j];
  if (ACT == 1) s = s / (1.f + expf(-s));
  outp[(size_t)b * n + j] = s;
}

// ---------------- dotk: constb[b] = qk[b] . cond[b] ----------------
__global__ __launch_bounds__(256) void dotk_kernel(const float* __restrict__ qk,
                                                   const float* __restrict__ cond,
                                                   float* __restrict__ cb) {
  __shared__ float red[4];
  const int b = blockIdx.x, tid = threadIdx.x;
  float c = qk[(size_t)b * 512 + tid] * cond[(size_t)b * 512 + tid] +
            qk[(size_t)b * 512 + tid + 256] * cond[(size_t)b * 512 + tid + 256];
  c = wave_sum64(c);
  if ((tid & 63) == 0) red[tid >> 6] = c;
  __syncthreads();
  if (tid == 0) cb[b] = red[0] + red[1] + red[2] + red[3];
}

// ---------------- K2: Wd1[:,512:] -> bf16 in fragment-major order ----------------
__global__ __launch_bounds__(256) void convw_kernel(const float* __restrict__ Wd1,
                                                    unsigned short* __restrict__ wsW) {
  const int g = blockIdx.x * 256 + threadIdx.x;  // 0..65535
  const int lane = g & 63;
  const int kc = (g >> 6) & 1;
  const int nhn = (g >> 7) & 7;
  const int ks = (g >> 10) & 7;
  const int nc = g >> 13;
  const int j = nc * 128 + (nhn >> 1) * 32 + (nhn & 1) * 16 + (lane & 15);
  const int k = ks * 64 + kc * 32 + (lane >> 4) * 8;
  const float* src = Wd1 + (size_t)j * 1024 + 512 + k;
  float4 f0 = *(const float4*)src;
  float4 f1 = *(const float4*)(src + 4);
  ushort4 h0 = make_ushort4(f2bf(f0.x), f2bf(f0.y), f2bf(f0.z), f2bf(f0.w));
  ushort4 h1 = make_ushort4(f2bf(f1.x), f2bf(f1.y), f2bf(f1.z), f2bf(f1.w));
  ushort4* dst = (ushort4*)((char*)wsW + (size_t)g * 16);
  dst[0] = h0;
  dst[1] = h1;
}

// ---------------- K3: logits (fp32 dot pass over te; optional bf16 te emit) ----------------
__global__ __launch_bounds__(256) void logits_kernel(
    const float* __restrict__ te, const float* __restrict__ qk,
    const float* __restrict__ constb, const float* __restrict__ x,
    float* __restrict__ logits, unsigned short* __restrict__ te16, int w16) {
  const int wave = threadIdx.x >> 6, lane = threadIdx.x & 63;
  const size_t r = (size_t)blockIdx.x * 4 + wave;
  const int b = (int)(r >> 10);
  const float4* t4 = (const float4*)(te + r * 512);
  const float4* q4 = (const float4*)(qk + (size_t)b * 512);
  float4 a0 = t4[lane], a1 = t4[lane + 64];
  float4 c0 = q4[lane], c1 = q4[lane + 64];
  float s = a0.x * c0.x + a0.y * c0.y + a0.z * c0.z + a0.w * c0.w +
            a1.x * c1.x + a1.y * c1.y + a1.z * c1.z + a1.w * c1.w;
  s = wave_sum64(s);
  if (w16) {
    ushort4 h0 = make_ushort4(f2bf(a0.x), f2bf(a0.y), f2bf(a0.z), f2bf(a0.w));
    ushort4 h1 = make_ushort4(f2bf(a1.x), f2bf(a1.y), f2bf(a1.z), f2bf(a1.w));
    *(ushort4*)(te16 + r * 512 + lane * 4) = h0;
    *(ushort4*)(te16 + r * 512 + 256 + lane * 4) = h1;
  }
  if (lane == 0) logits[r] = s + constb[b] + x[r];
}

// ---------------- K4: softmax per batch; also init out = w + bd2 ----------------
__global__ __launch_bounds__(256) void softmax_kernel(
    const float* __restrict__ logits, const float* __restrict__ bd2,
    float* __restrict__ weight, float* __restrict__ out) {
  __shared__ float sm[4];
  const int b = blockIdx.x, tid = threadIdx.x;
  const int wave = tid >> 6, lane = tid & 63;
  float4 l4 = ((const float4*)(logits + (size_t)b * 1024))[tid];
  float m = fmaxf(fmaxf(l4.x, l4.y), fmaxf(l4.z, l4.w));
#pragma unroll
  for (int o = 32; o; o >>= 1) m = fmaxf(m, __shfl_xor(m, o, 64));
  if (lane == 0) sm[wave] = m;
  __syncthreads();
  float M = fmaxf(fmaxf(sm[0], sm[1]), fmaxf(sm[2], sm[3]));
  __syncthreads();
  float e0 = expf(l4.x - M), e1 = expf(l4.y - M), e2 = expf(l4.z - M), e3 = expf(l4.w - M);
  float ssum = wave_sum64(e0 + e1 + e2 + e3);
  if (lane == 0) sm[wave] = ssum;
  __syncthreads();
  float inv = 1.f / (sm[0] + sm[1] + sm[2] + sm[3]);
  float c = bd2[0];
  float4 w4 = make_float4(e0 * inv, e1 * inv, e2 * inv, e3 * inv);
  ((float4*)(weight + (size_t)b * 1024))[tid] = w4;
  ((float4*)(out + (size_t)b * 1024))[tid] = make_float4(w4.x + c, w4.y + c, w4.z + c, w4.w + c);
}

// ---------------- K5a: spart[(b,vq)][d] = sum_{v in chunk} w * te  (fp32 input) ----------------
__global__ __launch_bounds__(256) void wsum32_kernel(const float* __restrict__ te,
                                                     const float* __restrict__ weight,
                                                     float* __restrict__ spart) {
  __shared__ float wl[128];
  const int b = blockIdx.x >> 3, vq = blockIdx.x & 7;
  const int tid = threadIdx.x;
  if (tid < 128) wl[tid] = weight[(size_t)b * 1024 + vq * 128 + tid];
  __syncthreads();
  const float* tb = te + ((size_t)b * 1024 + (size_t)vq * 128) * 512;
  float s0 = 0.f, s1 = 0.f;
#pragma unroll 4
  for (int v = 0; v < 128; ++v) {
    float w = wl[v];
    s0 += w * tb[(size_t)v * 512 + tid];
    s1 += w * tb[(size_t)v * 512 + 256 + tid];
  }
  spart[(size_t)blockIdx.x * 512 + tid] = s0;
  spart[(size_t)blockIdx.x * 512 + 256 + tid] = s1;
}

// ---------------- K5a': same from bf16 te ----------------
__global__ __launch_bounds__(256) void wsum16_kernel(const unsigned short* __restrict__ te16,
                                                     const float* __restrict__ weight,
                                                     float* __restrict__ spart) {
  __shared__ float wl[128];
  __shared__ float red[4][512];
  const int b = blockIdx.x >> 3, vq = blockIdx.x & 7;
  const int tid = threadIdx.x;
  if (tid < 128) wl[tid] = weight[(size_t)b * 1024 + vq * 128 + tid];
  __syncthreads();
  const int g = tid & 63, vh = tid >> 6;
  const unsigned short* base =
      te16 + ((size_t)b * 1024 + vq * 128 + vh * 32) * 512 + g * 8;
  float acc[8] = {};
  for (int v = 0; v < 32; ++v) {
    float w = wl[vh * 32 + v];
    ushort8_t h = *(const ushort8_t*)(base + (size_t)v * 512);
#pragma unroll
    for (int i = 0; i < 8; ++i) acc[i] += w * bf2f(h[i]);
  }
#pragma unroll
  for (int i = 0; i < 8; ++i) red[vh][g * 8 + i] = acc[i];
  __syncthreads();
  for (int d = tid; d < 512; d += 256)
    spart[(size_t)blockIdx.x * 512 + d] =
        red[0][d] + red[1][d] + red[2][d] + red[3][d];
}

// ---------------- K6: decoder GEMM + fused epilogue ----------------
// 2048 blocks x 512 thr (8 waves: 2M x 4N). Block: 64 te-rows x N=1024, K=512.
// LDS: te [64 rows][512 bf16] XOR-swizzled = 64 KiB. W global fragment-major
// (L2-resident), register double-buffered; no K-loop barriers.
__global__ __launch_bounds__(512) void decoder_kernel(
    const float* __restrict__ te, const unsigned short* __restrict__ te16, int use16,
    const unsigned short* __restrict__ wsW, const float* __restrict__ A,
    const float* __restrict__ Wd2, float* __restrict__ out) {
  extern __shared__ char te_lds[];  // 65536 B

  const int tid = threadIdx.x;
  const int wave = tid >> 6, lane = tid & 63;
  const int lhi = lane >> 4, llo = lane & 15;
  const int mh = wave >> 2, nh = wave & 3;
  const size_t row0 = (size_t)blockIdx.x * 64;
  const int b = (int)(blockIdx.x >> 4);

  if (use16) {
    const char* t16 = (const char*)(te16 + row0 * 512);
#pragma unroll
    for (int it = 0; it < 8; ++it) {
      int u = it * 512 + tid;        // 16B unit; 4096 total
      int r = u >> 6, c = u & 63;    // row, 16B-col
      int4 v = *(const int4*)(t16 + (size_t)r * 1024 + c * 16);
      *(int4*)(te_lds + r * 1024 + ((c * 16) ^ ((r & 7) << 4))) = v;
    }
  } else {
    const float4* te4 = (const float4*)(te + row0 * 512);
#pragma unroll
    for (int it = 0; it < 16; ++it) {
      int f = it * 512 + tid;
      int r = f >> 7, c4 = f & 127;
      float4 v = te4[f];
      ushort4 h = make_ushort4(f2bf(v.x), f2bf(v.y), f2bf(v.z), f2bf(v.w));
      *(ushort4*)(te_lds + r * 1024 + ((c4 * 8) ^ ((r & 7) << 4))) = h;
    }
  }
  __syncthreads();

  int aoff[2][2];
#pragma unroll
  for (int m = 0; m < 2; ++m)
#pragma unroll
    for (int kc = 0; kc < 2; ++kc) {
      int r = mh * 32 + m * 16 + llo;
      aoff[m][kc] = r * 1024 + ((kc * 64 + lhi * 16) ^ ((r & 7) << 4));
    }

  const char* wbase = (const char*)wsW + nh * 4096 + lane * 16;
  const float* A_g = A + (size_t)b * 1024;

  float pacc[2][4] = {};
  fx4_t acc[2][2];
  const fx4_t zf = {0.f, 0.f, 0.f, 0.f};
  bhalf8_t bwA[2][2], bwB[2][2];

  auto loadw = [&](bhalf8_t (&dst)[2][2], int c) {
    const char* p = wbase + (size_t)c * 16384;
#pragma unroll
    for (int n = 0; n < 2; ++n)
#pragma unroll
      for (int kc = 0; kc < 2; ++kc)
        dst[n][kc] = *(const bhalf8_t*)(p + n * 2048 + kc * 1024);
  };

  auto body = [&](bhalf8_t (&bw)[2][2], int c) {
    const int nc = c >> 3, ks = c & 7;
    if (ks == 0) {
      acc[0][0] = zf; acc[0][1] = zf; acc[1][0] = zf; acc[1][1] = zf;
    }
    const char* tb = te_lds + ks * 128;
#pragma unroll
    for (int kc = 0; kc < 2; ++kc) {
      bhalf8_t a0 = *(const bhalf8_t*)(tb + aoff[0][kc]);
      bhalf8_t a1 = *(const bhalf8_t*)(tb + aoff[1][kc]);
      acc[0][0] = __builtin_amdgcn_mfma_f32_16x16x32_bf16(a0, bw[0][kc], acc[0][0], 0, 0, 0);
      acc[0][1] = __builtin_amdgcn_mfma_f32_16x16x32_bf16(a0, bw[1][kc], acc[0][1], 0, 0, 0);
      acc[1][0] = __builtin_amdgcn_mfma_f32_16x16x32_bf16(a1, bw[0][kc], acc[1][0], 0, 0, 0);
      acc[1][1] = __builtin_amdgcn_mfma_f32_16x16x32_bf16(a1, bw[1][kc], acc[1][1], 0, 0, 0);
    }
    if (ks == 7) {
      const int jb = nc * 128 + nh * 32;
#pragma unroll
      for (int n = 0; n < 2; ++n) {
        const int j = jb + n * 16 + llo;
        const float av = A_g[j];
        const float wv = Wd2[j];
#pragma unroll
        for (int m = 0; m < 2; ++m)
#pragma unroll
          for (int rg = 0; rg < 4; ++rg)
            pacc[m][rg] += fmaxf(acc[m][n][rg] + av, 0.f) * wv;
      }
    }
  };

  loadw(bwA, 0);
  for (int cp = 0; cp < 32; ++cp) {
    loadw(bwB, cp * 2 + 1);
    body(bwA, cp * 2);
    if (cp < 31) loadw(bwA, cp * 2 + 2);
    body(bwB, cp * 2 + 1);
  }

  __syncthreads();
  float* red = (float*)te_lds;  // [4 nh][64 rows]
#pragma unroll
  for (int m = 0; m < 2; ++m)
#pragma unroll
    for (int rg = 0; rg < 4; ++rg) {
      float sv = pacc[m][rg];
      sv += __shfl_xor(sv, 1, 64);
      sv += __shfl_xor(sv, 2, 64);
      sv += __shfl_xor(sv, 4, 64);
      sv += __shfl_xor(sv, 8, 64);
      if (llo == 0) red[nh * 64 + mh * 32 + m * 16 + lhi * 4 + rg] = sv;
    }
  __syncthreads();
  if (tid < 64) {
    float s = red[tid] + red[64 + tid] + red[128 + tid] + red[192 + tid];
    out[row0 + tid] += s;  // out pre-initialized to w + bd2; rows exclusive per block
  }
}

// ---------------- launch ----------------
extern "C" void kernel_launch(void* const* d_in, const int* in_sizes, int n_in,
                              void* d_out, int out_size, void* d_ws, size_t ws_size,
                              hipStream_t stream) {
  const float* x = (const float*)d_in[0];
  const int* tsteps = (const int*)d_in[1];
  const float* qe = (const float*)d_in[2];
  const float* te = (const float*)d_in[3];
  const float* Wq = (const float*)d_in[4];
  const float* Wk = (const float*)d_in[5];
  const float* Wv = (const float*)d_in[6];
  const float* Wp = (const float*)d_in[7];
  const float* bp = (const float*)d_in[8];
  const float* Wt1 = (const float*)d_in[9];
  const float* bt1 = (const float*)d_in[10];
  const float* Wt2 = (const float*)d_in[11];
  const float* bt2 = (const float*)d_in[12];
  const float* Wd1 = (const float*)d_in[13];
  const float* bd1 = (const float*)d_in[14];
  const float* Wd2 = (const float*)d_in[15];
  const float* bd2 = (const float*)d_in[16];
  float* out = (float*)d_out;

  char* ws = (char*)d_ws;
  unsigned short* wsW = (unsigned short*)(ws + 0);     // 1 MB
  float* Wt1T = (float*)(ws + 1048576);                // 1 MB each
  float* Wt2T = (float*)(ws + 2097152);
  float* WqT = (float*)(ws + 3145728);
  float* WvT = (float*)(ws + 4194304);
  float* WpT = (float*)(ws + 5242880);
  float* Wd1aT = (float*)(ws + 6291456);               // 2 MB [512][1024]
  float* cond = (float*)(ws + 8388608);                // 256 KB each
  float* qk = (float*)(ws + 8650752);
  float* hbuf = (float*)(ws + 8912896);
  float* qbuf = (float*)(ws + 9175040);
  float* ubuf = (float*)(ws + 9437184);
  float* nebuf = (float*)(ws + 9699328);
  float* cb = (float*)(ws + 9961472);                  // 4 KB slot
  float* logits = (float*)(ws + 9965568);              // 512 KB
  float* wgt = (float*)(ws + 10489856);                // 512 KB
  float* spart = (float*)(ws + 11014144);              // 2 MB [128*8][512]
  float* Abuf = (float*)(ws + 13111296);               // 512 KB
  const size_t TE16_OFF = 14680064;                    // 14 MB, 1MB-aligned
  const size_t TE16_BYTES = (size_t)128 * 1024 * 512 * 2;  // 128 MB
  unsigned short* te16 = (unsigned short*)(ws + TE16_OFF);
  const int use16 = (ws_size >= TE16_OFF + TE16_BYTES) ? 1 : 0;

  // weight transposes (coalesced mat-vec reads) + decoder W pre-pack
  transpose_kernel<<<dim3(16, 16), 256, 0, stream>>>(Wt1, Wt1T, 512, 512);
  transpose_kernel<<<dim3(16, 16), 256, 0, stream>>>(Wt2, Wt2T, 512, 512);
  transpose_kernel<<<dim3(16, 16), 256, 0, stream>>>(Wq, WqT, 512, 512);
  transpose_kernel<<<dim3(16, 16), 256, 0, stream>>>(Wv, WvT, 512, 512);
  transpose_kernel<<<dim3(16, 16), 256, 0, stream>>>(Wp, WpT, 512, 512);
  transpose_kernel<<<dim3(16, 32), 256, 0, stream>>>(Wd1, Wd1aT, 1024, 1024);
  convw_kernel<<<256, 256, 0, stream>>>(Wd1, wsW);

  // cond / q / qk chain (batched mat-vecs)
  gvec_kernel<0, 1><<<dim3(128, 2), 256, 0, stream>>>(Wt1T, 512, nullptr, nullptr, bt1, tsteps, hbuf);
  gvec_kernel<1, 0><<<dim3(128, 2), 256, 0, stream>>>(Wt2T, 512, hbuf, nullptr, bt2, nullptr, cond);
  gvec_kernel<2, 0><<<dim3(128, 2), 256, 0, stream>>>(WqT, 512, qe, cond, nullptr, nullptr, qbuf);
  gvec_kernel<1, 0><<<dim3(128, 2), 256, 0, stream>>>(Wk, 512, qbuf, nullptr, nullptr, nullptr, qk);
  dotk_kernel<<<128, 256, 0, stream>>>(qk, cond, cb);

  logits_kernel<<<32768, 256, 0, stream>>>(te, qk, cb, x, logits, te16, use16);
  softmax_kernel<<<128, 256, 0, stream>>>(logits, bd2, wgt, out);
  if (use16)
    wsum16_kernel<<<1024, 256, 0, stream>>>(te16, wgt, spart);
  else
    wsum32_kernel<<<1024, 256, 0, stream>>>(te, wgt, spart);

  // new_emb -> A chain
  gvec_kernel<3, 0><<<dim3(128, 2), 256, 0, stream>>>(WvT, 512, spart, cond, nullptr, nullptr, ubuf);
  gvec_kernel<1, 0><<<dim3(128, 2), 256, 0, stream>>>(WpT, 512, ubuf, nullptr, bp, nullptr, nebuf);
  gvec_kernel<1, 0><<<dim3(128, 4), 256, 0, stream>>>(Wd1aT, 1024, nebuf, nullptr, bd1, nullptr, Abuf);

  (void)hipFuncSetAttribute((const void*)decoder_kernel,
                            hipFuncAttributeMaxDynamicSharedMemorySize, 65536);
  decoder_kernel<<<2048, 512, 65536, stream>>>(te, te16, use16, wsW, Abuf, Wd2, out);
}

// Round 4
// 430.432 us; speedup vs baseline: 2.7315x; 1.1968x over previous
//
#include <hip/hip_runtime.h>
#include <hip/hip_bf16.h>

// Diffusion decoder, algebraically factored:
//   cond_b = MLP(pe[t_b]);  q_b = Wq@(qe_b+cond_b);  qk_b = q_b @ Wk
//   logit[b,v] = qk_b . te[b,v] + qk_b.cond_b + x[b,v]       (fp32 pass over te)
//   w = softmax(logit); s_b = sum_v w te[b,v]                (bf16 pass over te)
//   new_emb_b = Wp@(Wv@(s_b+cond_b)) + bp
//   A_b = Wd1[:, :512]@new_emb_b + bd1
//   p[b,v] = Wd2 . relu(A_b + Wd1[:,512:]@te[b,v]) + bd2 + w (bf16 MFMA GEMM, fused epilogue)
//
// v4 decoder: A (te) fragments in registers (loaded once from te16), W chunks
// LDS-staged via global_load_lds into a 4x16KB ring shared by all 8 waves
// (W L2 traffic 4GB -> 2GB), depth-3 prefetch with counted vmcnt + barrier.

typedef __attribute__((ext_vector_type(8))) short bhalf8_t;   // 8 bf16 in 4 VGPRs
typedef __attribute__((ext_vector_type(8))) unsigned short ushort8_t;
typedef __attribute__((ext_vector_type(4))) float fx4_t;

__device__ __forceinline__ unsigned short f2bf(float f) {
  unsigned int u = __float_as_uint(f);
  unsigned int r = (u + 0x7FFFu + ((u >> 16) & 1u)) >> 16;  // RNE
  return (unsigned short)r;
}
__device__ __forceinline__ float bf2f(unsigned short h) {
  return __uint_as_float((unsigned int)h << 16);
}

__device__ __forceinline__ float wave_sum64(float s) {
#pragma unroll
  for (int o = 32; o; o >>= 1) s += __shfl_xor(s, o, 64);
  return s;
}

// ---------------- T: five 512x512 transposes in one launch ----------------
__global__ __launch_bounds__(256) void transpose5_kernel(
    const float* __restrict__ s0, const float* __restrict__ s1, const float* __restrict__ s2,
    const float* __restrict__ s3, const float* __restrict__ s4,
    float* __restrict__ d0, float* __restrict__ d1, float* __restrict__ d2,
    float* __restrict__ d3, float* __restrict__ d4) {
  __shared__ float t[32][33];
  const float* src; float* dst;
  switch (blockIdx.z) {
    case 0: src = s0; dst = d0; break;
    case 1: src = s1; dst = d1; break;
    case 2: src = s2; dst = d2; break;
    case 3: src = s3; dst = d3; break;
    default: src = s4; dst = d4; break;
  }
  const int tx = threadIdx.x & 31, ty = threadIdx.x >> 5;
  const int c0 = blockIdx.x * 32, r0 = blockIdx.y * 32;
#pragma unroll
  for (int i = 0; i < 32; i += 8)
    t[ty + i][tx] = src[(size_t)(r0 + ty + i) * 512 + c0 + tx];
  __syncthreads();
#pragma unroll
  for (int i = 0; i < 32; i += 8)
    dst[(size_t)(c0 + ty + i) * 512 + r0 + tx] = t[tx][ty + i];
}

// ---------------- T': transpose Wd1[:, :512] (1024 rows) -> Wd1aT [512][1024] ----------------
__global__ __launch_bounds__(256) void transposed1_kernel(const float* __restrict__ src,
                                                          float* __restrict__ dst) {
  __shared__ float t[32][33];
  const int tx = threadIdx.x & 31, ty = threadIdx.x >> 5;
  const int c0 = blockIdx.x * 32, r0 = blockIdx.y * 32;
#pragma unroll
  for (int i = 0; i < 32; i += 8)
    t[ty + i][tx] = src[(size_t)(r0 + ty + i) * 1024 + c0 + tx];
  __syncthreads();
#pragma unroll
  for (int i = 0; i < 32; i += 8)
    dst[(size_t)(c0 + ty + i) * 1024 + r0 + tx] = t[tx][ty + i];
}

// ---------------- G: batched mat-vec  out[b][j] = act(bias[j] + sum_k arow[b][k] * WT[k][j]) ----------------
// MODE: 0 = arow from sinusoidal PE of timesteps[b]; 1 = src1[b]; 2 = src1[b]+src2[b];
//       3 = src2[b] + sum_{q<8} src1[(b*8+q)*512]
template <int MODE, int ACT>
__global__ __launch_bounds__(256) void gvec_kernel(
    const float* __restrict__ WT, int n, const float* __restrict__ src1,
    const float* __restrict__ src2, const float* __restrict__ bias,
    const int* __restrict__ timesteps, float* __restrict__ outp) {
  __shared__ __attribute__((aligned(16))) float arow[512];
  const int b = blockIdx.x, tid = threadIdx.x;
  if (MODE == 0) {
    const int ts = timesteps[b];
    const float NEG = -9.2103403719761836f / 512.f;  // -ln(10000)/512
    float dv = expf((float)(2 * tid) * NEG);
    float ang = (float)ts * dv;
    arow[2 * tid] = sinf(ang);
    arow[2 * tid + 1] = cosf(ang);
  } else {
#pragma unroll
    for (int k = tid; k < 512; k += 256) {
      float a;
      if (MODE == 1) {
        a = src1[(size_t)b * 512 + k];
      } else if (MODE == 2) {
        a = src1[(size_t)b * 512 + k] + src2[(size_t)b * 512 + k];
      } else {
        a = src2[(size_t)b * 512 + k];
#pragma unroll
        for (int q = 0; q < 8; ++q) a += src1[((size_t)b * 8 + q) * 512 + k];
      }
      arow[k] = a;
    }
  }
  __syncthreads();
  const int j = blockIdx.y * 256 + tid;
  const float* w = WT + j;
  float s0 = 0.f, s1 = 0.f, s2 = 0.f, s3 = 0.f;
#pragma unroll 4
  for (int k = 0; k < 512; k += 4) {
    s0 = fmaf(arow[k], w[(size_t)k * n], s0);
    s1 = fmaf(arow[k + 1], w[(size_t)(k + 1) * n], s1);
    s2 = fmaf(arow[k + 2], w[(size_t)(k + 2) * n], s2);
    s3 = fmaf(arow[k + 3], w[(size_t)(k + 3) * n], s3);
  }
  float s = (s0 + s1) + (s2 + s3);
  if (bias) s += bias[j];
  if (ACT == 1) s = s / (1.f + expf(-s));
  outp[(size_t)b * n + j] = s;
}

// ---------------- dotk: constb[b] = qk[b] . cond[b] ----------------
__global__ __launch_bounds__(256) void dotk_kernel(const float* __restrict__ qk,
                                                   const float* __restrict__ cond,
                                                   float* __restrict__ cb) {
  __shared__ float red[4];
  const int b = blockIdx.x, tid = threadIdx.x;
  float c = qk[(size_t)b * 512 + tid] * cond[(size_t)b * 512 + tid] +
            qk[(size_t)b * 512 + tid + 256] * cond[(size_t)b * 512 + tid + 256];
  c = wave_sum64(c);
  if ((tid & 63) == 0) red[tid >> 6] = c;
  __syncthreads();
  if (tid == 0) cb[b] = red[0] + red[1] + red[2] + red[3];
}

// ---------------- K2: Wd1[:,512:] -> bf16 in fragment-major order ----------------
// byte addr g*16, g = lane | kc<<6 | (nh*2+n)<<7 | ks<<10 | nc<<13
// holds W[j][k..k+7], j = nc*128+nh*32+n*16+(lane&15), k = ks*64+kc*32+(lane>>4)*8
__global__ __launch_bounds__(256) void convw_kernel(const float* __restrict__ Wd1,
                                                    unsigned short* __restrict__ wsW) {
  const int g = blockIdx.x * 256 + threadIdx.x;  // 0..65535
  const int lane = g & 63;
  const int kc = (g >> 6) & 1;
  const int nhn = (g >> 7) & 7;
  const int ks = (g >> 10) & 7;
  const int nc = g >> 13;
  const int j = nc * 128 + (nhn >> 1) * 32 + (nhn & 1) * 16 + (lane & 15);
  const int k = ks * 64 + kc * 32 + (lane >> 4) * 8;
  const float* src = Wd1 + (size_t)j * 1024 + 512 + k;
  float4 f0 = *(const float4*)src;
  float4 f1 = *(const float4*)(src + 4);
  ushort4 h0 = make_ushort4(f2bf(f0.x), f2bf(f0.y), f2bf(f0.z), f2bf(f0.w));
  ushort4 h1 = make_ushort4(f2bf(f1.x), f2bf(f1.y), f2bf(f1.z), f2bf(f1.w));
  ushort4* dst = (ushort4*)((char*)wsW + (size_t)g * 16);
  dst[0] = h0;
  dst[1] = h1;
}

// ---------------- K3: logits (fp32 dot pass over te; optional bf16 te emit) ----------------
__global__ __launch_bounds__(256) void logits_kernel(
    const float* __restrict__ te, const float* __restrict__ qk,
    const float* __restrict__ constb, const float* __restrict__ x,
    float* __restrict__ logits, unsigned short* __restrict__ te16, int w16) {
  const int wave = threadIdx.x >> 6, lane = threadIdx.x & 63;
  const size_t r = (size_t)blockIdx.x * 4 + wave;
  const int b = (int)(r >> 10);
  const float4* t4 = (const float4*)(te + r * 512);
  const float4* q4 = (const float4*)(qk + (size_t)b * 512);
  float4 a0 = t4[lane], a1 = t4[lane + 64];
  float4 c0 = q4[lane], c1 = q4[lane + 64];
  float s = a0.x * c0.x + a0.y * c0.y + a0.z * c0.z + a0.w * c0.w +
            a1.x * c1.x + a1.y * c1.y + a1.z * c1.z + a1.w * c1.w;
  s = wave_sum64(s);
  if (w16) {
    ushort4 h0 = make_ushort4(f2bf(a0.x), f2bf(a0.y), f2bf(a0.z), f2bf(a0.w));
    ushort4 h1 = make_ushort4(f2bf(a1.x), f2bf(a1.y), f2bf(a1.z), f2bf(a1.w));
    *(ushort4*)(te16 + r * 512 + lane * 4) = h0;
    *(ushort4*)(te16 + r * 512 + 256 + lane * 4) = h1;
  }
  if (lane == 0) logits[r] = s + constb[b] + x[r];
}

// ---------------- K4: softmax per batch; also init out = w + bd2 ----------------
__global__ __launch_bounds__(256) void softmax_kernel(
    const float* __restrict__ logits, const float* __restrict__ bd2,
    float* __restrict__ weight, float* __restrict__ out) {
  __shared__ float sm[4];
  const int b = blockIdx.x, tid = threadIdx.x;
  const int wave = tid >> 6, lane = tid & 63;
  float4 l4 = ((const float4*)(logits + (size_t)b * 1024))[tid];
  float m = fmaxf(fmaxf(l4.x, l4.y), fmaxf(l4.z, l4.w));
#pragma unroll
  for (int o = 32; o; o >>= 1) m = fmaxf(m, __shfl_xor(m, o, 64));
  if (lane == 0) sm[wave] = m;
  __syncthreads();
  float M = fmaxf(fmaxf(sm[0], sm[1]), fmaxf(sm[2], sm[3]));
  __syncthreads();
  float e0 = expf(l4.x - M), e1 = expf(l4.y - M), e2 = expf(l4.z - M), e3 = expf(l4.w - M);
  float ssum = wave_sum64(e0 + e1 + e2 + e3);
  if (lane == 0) sm[wave] = ssum;
  __syncthreads();
  float inv = 1.f / (sm[0] + sm[1] + sm[2] + sm[3]);
  float c = bd2[0];
  float4 w4 = make_float4(e0 * inv, e1 * inv, e2 * inv, e3 * inv);
  ((float4*)(weight + (size_t)b * 1024))[tid] = w4;
  ((float4*)(out + (size_t)b * 1024))[tid] = make_float4(w4.x + c, w4.y + c, w4.z + c, w4.w + c);
}

// ---------------- K5a: spart[(b,vq)][d] = sum_{v in chunk} w * te  (fp32 input) ----------------
__global__ __launch_bounds__(256) void wsum32_kernel(const float* __restrict__ te,
                                                     const float* __restrict__ weight,
                                                     float* __restrict__ spart) {
  __shared__ float wl[128];
  const int b = blockIdx.x >> 3, vq = blockIdx.x & 7;
  const int tid = threadIdx.x;
  if (tid < 128) wl[tid] = weight[(size_t)b * 1024 + vq * 128 + tid];
  __syncthreads();
  const float* tb = te + ((size_t)b * 1024 + (size_t)vq * 128) * 512;
  float s0 = 0.f, s1 = 0.f;
#pragma unroll 4
  for (int v = 0; v < 128; ++v) {
    float w = wl[v];
    s0 += w * tb[(size_t)v * 512 + tid];
    s1 += w * tb[(size_t)v * 512 + 256 + tid];
  }
  spart[(size_t)blockIdx.x * 512 + tid] = s0;
  spart[(size_t)blockIdx.x * 512 + 256 + tid] = s1;
}

// ---------------- K5a': same from bf16 te ----------------
__global__ __launch_bounds__(256) void wsum16_kernel(const unsigned short* __restrict__ te16,
                                                     const float* __restrict__ weight,
                                                     float* __restrict__ spart) {
  __shared__ float wl[128];
  __shared__ float red[4][512];
  const int b = blockIdx.x >> 3, vq = blockIdx.x & 7;
  const int tid = threadIdx.x;
  if (tid < 128) wl[tid] = weight[(size_t)b * 1024 + vq * 128 + tid];
  __syncthreads();
  const int g = tid & 63, vh = tid >> 6;
  const unsigned short* base =
      te16 + ((size_t)b * 1024 + vq * 128 + vh * 32) * 512 + g * 8;
  float acc[8] = {};
  for (int v = 0; v < 32; ++v) {
    float w = wl[vh * 32 + v];
    ushort8_t h = *(const ushort8_t*)(base + (size_t)v * 512);
#pragma unroll
    for (int i = 0; i < 8; ++i) acc[i] += w * bf2f(h[i]);
  }
#pragma unroll
  for (int i = 0; i < 8; ++i) red[vh][g * 8 + i] = acc[i];
  __syncthreads();
  for (int d = tid; d < 512; d += 256)
    spart[(size_t)blockIdx.x * 512 + d] =
        red[0][d] + red[1][d] + red[2][d] + red[3][d];
}

// ---------------- K6: decoder GEMM + fused epilogue ----------------
// 2048 blocks x 512 thr (8 waves: 2mh x 4nh). Block: 64 te-rows x N=1024, K=512.
// A (te) in registers: 32 frags/wave. W: 64 chunks of 16KB (frag-major wsW),
// LDS-staged via global_load_lds into 4x16KB ring, depth-3 counted-vmcnt pipeline.
#define GLD16(g, l)                                                              \
  __builtin_amdgcn_global_load_lds((const __attribute__((address_space(1))) void*)(g), \
                                   (__attribute__((address_space(3))) void*)(l), 16, 0, 0)

template <int USE16>
__global__ __launch_bounds__(512, 2) void decoder_kernel(
    const float* __restrict__ te, const unsigned short* __restrict__ te16,
    const unsigned short* __restrict__ wsW, const float* __restrict__ A,
    const float* __restrict__ Wd2, float* __restrict__ out) {
  extern __shared__ char lds[];  // 4 x 16384 B W ring

  const int tid = threadIdx.x;
  const int wave = tid >> 6, lane = tid & 63;
  const int lhi = lane >> 4, llo = lane & 15;
  const int mh = wave >> 2, nh = wave & 3;
  const size_t row0 = (size_t)blockIdx.x * 64;
  const int b = (int)(blockIdx.x >> 4);

  // ---- A fragments -> registers: a[m][slot], slot = ks*2+kc (k = slot*32 + lhi*8) ----
  bhalf8_t a[2][16];
  if (USE16) {
#pragma unroll
    for (int m = 0; m < 2; ++m) {
      const char* rowp = (const char*)te16 + (row0 + mh * 32 + m * 16 + llo) * 1024 + lhi * 16;
#pragma unroll
      for (int s = 0; s < 16; ++s) a[m][s] = *(const bhalf8_t*)(rowp + s * 64);
    }
  } else {
#pragma unroll
    for (int m = 0; m < 2; ++m) {
      const char* rowp = (const char*)te + (row0 + mh * 32 + m * 16 + llo) * 2048 + lhi * 32;
#pragma unroll
      for (int s = 0; s < 16; ++s) {
        float4 f0 = *(const float4*)(rowp + s * 128);
        float4 f1 = *(const float4*)(rowp + s * 128 + 16);
        bhalf8_t h;
        h[0] = (short)f2bf(f0.x); h[1] = (short)f2bf(f0.y);
        h[2] = (short)f2bf(f0.z); h[3] = (short)f2bf(f0.w);
        h[4] = (short)f2bf(f1.x); h[5] = (short)f2bf(f1.y);
        h[6] = (short)f2bf(f1.z); h[7] = (short)f2bf(f1.w);
        a[m][s] = h;
      }
    }
  }

  // ---- W staging: chunk c occupies wsW bytes [c*16384, +16384) as [nhn(8)|kc(2)|lane(64)|16B] ----
  auto stage = [&](int c) {
    const char* src = (const char*)wsW + (size_t)c * 16384 + wave * 1024 + lane * 16;
    char* dst = lds + (c & 3) * 16384 + wave * 1024;  // HW adds lane*16
    GLD16(src, dst);
    GLD16(src + 8192, dst + 8192);
  };
  stage(0); stage(1); stage(2);

  const float* A_g = A + (size_t)b * 1024;
  fx4_t acc[2][2];
  const fx4_t zf = {0.f, 0.f, 0.f, 0.f};
  float pacc[2][4] = {};

  for (int nc = 0; nc < 8; ++nc) {
    const int jb = nc * 128 + nh * 32 + llo;
    float av0 = A_g[jb], av1 = A_g[jb + 16];
    float wv0 = Wd2[jb], wv1 = Wd2[jb + 16];
#pragma unroll
    for (int ks = 0; ks < 8; ++ks) {
      const int c = nc * 8 + ks;
      // chunk-c stage complete when own outstanding <= 2*(stages issued beyond c)
      if (ks == 6) {
        if (nc == 7) asm volatile("s_waitcnt vmcnt(2)" ::: "memory");
        else         asm volatile("s_waitcnt vmcnt(4)" ::: "memory");
      } else if (ks == 7) {
        if (nc == 7) asm volatile("s_waitcnt vmcnt(0)" ::: "memory");
        else         asm volatile("s_waitcnt vmcnt(4)" ::: "memory");
      } else {
        asm volatile("s_waitcnt vmcnt(4)" ::: "memory");
      }
      __builtin_amdgcn_s_barrier();
      __builtin_amdgcn_sched_barrier(0);
      if (ks == 0) { acc[0][0] = zf; acc[0][1] = zf; acc[1][0] = zf; acc[1][1] = zf; }
      const char* wb = lds + (ks & 3) * 16384 + nh * 4096 + lane * 16;
      bhalf8_t b00 = *(const bhalf8_t*)(wb);
      bhalf8_t b01 = *(const bhalf8_t*)(wb + 1024);
      bhalf8_t b10 = *(const bhalf8_t*)(wb + 2048);
      bhalf8_t b11 = *(const bhalf8_t*)(wb + 3072);
      acc[0][0] = __builtin_amdgcn_mfma_f32_16x16x32_bf16(a[0][ks * 2 + 0], b00, acc[0][0], 0, 0, 0);
      acc[0][0] = __builtin_amdgcn_mfma_f32_16x16x32_bf16(a[0][ks * 2 + 1], b01, acc[0][0], 0, 0, 0);
      acc[0][1] = __builtin_amdgcn_mfma_f32_16x16x32_bf16(a[0][ks * 2 + 0], b10, acc[0][1], 0, 0, 0);
      acc[0][1] = __builtin_amdgcn_mfma_f32_16x16x32_bf16(a[0][ks * 2 + 1], b11, acc[0][1], 0, 0, 0);
      acc[1][0] = __builtin_amdgcn_mfma_f32_16x16x32_bf16(a[1][ks * 2 + 0], b00, acc[1][0], 0, 0, 0);
      acc[1][0] = __builtin_amdgcn_mfma_f32_16x16x32_bf16(a[1][ks * 2 + 1], b01, acc[1][0], 0, 0, 0);
      acc[1][1] = __builtin_amdgcn_mfma_f32_16x16x32_bf16(a[1][ks * 2 + 0], b10, acc[1][1], 0, 0, 0);
      acc[1][1] = __builtin_amdgcn_mfma_f32_16x16x32_bf16(a[1][ks * 2 + 1], b11, acc[1][1], 0, 0, 0);
      if (ks < 5) {
        stage(c + 3);
      } else if (nc < 7) {
        stage(c + 3);
      }
      if (ks == 7) {  // epilogue for this 128-col chunk (registers only)
#pragma unroll
        for (int m = 0; m < 2; ++m)
#pragma unroll
          for (int rg = 0; rg < 4; ++rg)
            pacc[m][rg] += fmaxf(acc[m][0][rg] + av0, 0.f) * wv0 +
                           fmaxf(acc[m][1][rg] + av1, 0.f) * wv1;
      }
    }
  }

  // block-level reduction across the 4 nh-waves (LDS ring is dead & drained)
  __syncthreads();
  float* red = (float*)lds;  // [4 nh][64 rows]
#pragma unroll
  for (int m = 0; m < 2; ++m)
#pragma unroll
    for (int rg = 0; rg < 4; ++rg) {
      float sv = pacc[m][rg];
      sv += __shfl_xor(sv, 1, 64);
      sv += __shfl_xor(sv, 2, 64);
      sv += __shfl_xor(sv, 4, 64);
      sv += __shfl_xor(sv, 8, 64);
      if (llo == 0) red[nh * 64 + mh * 32 + m * 16 + lhi * 4 + rg] = sv;
    }
  __syncthreads();
  if (tid < 64) {
    float s = red[tid] + red[64 + tid] + red[128 + tid] + red[192 + tid];
    out[row0 + tid] += s;  // out pre-initialized to w + bd2; rows exclusive per block
  }
}

// ---------------- launch ----------------
extern "C" void kernel_launch(void* const* d_in, const int* in_sizes, int n_in,
                              void* d_out, int out_size, void* d_ws, size_t ws_size,
                              hipStream_t stream) {
  const float* x = (const float*)d_in[0];
  const int* tsteps = (const int*)d_in[1];
  const float* qe = (const float*)d_in[2];
  const float* te = (const float*)d_in[3];
  const float* Wq = (const float*)d_in[4];
  const float* Wk = (const float*)d_in[5];
  const float* Wv = (const float*)d_in[6];
  const float* Wp = (const float*)d_in[7];
  const float* bp = (const float*)d_in[8];
  const float* Wt1 = (const float*)d_in[9];
  const float* bt1 = (const float*)d_in[10];
  const float* Wt2 = (const float*)d_in[11];
  const float* bt2 = (const float*)d_in[12];
  const float* Wd1 = (const float*)d_in[13];
  const float* bd1 = (const float*)d_in[14];
  const float* Wd2 = (const float*)d_in[15];
  const float* bd2 = (const float*)d_in[16];
  float* out = (float*)d_out;

  char* ws = (char*)d_ws;
  unsigned short* wsW = (unsigned short*)(ws + 0);     // 1 MB
  float* Wt1T = (float*)(ws + 1048576);                // 1 MB each
  float* Wt2T = (float*)(ws + 2097152);
  float* WqT = (float*)(ws + 3145728);
  float* WvT = (float*)(ws + 4194304);
  float* WpT = (float*)(ws + 5242880);
  float* Wd1aT = (float*)(ws + 6291456);               // 2 MB [512][1024]
  float* cond = (float*)(ws + 8388608);                // 256 KB each
  float* qk = (float*)(ws + 8650752);
  float* hbuf = (float*)(ws + 8912896);
  float* qbuf = (float*)(ws + 9175040);
  float* ubuf = (float*)(ws + 9437184);
  float* nebuf = (float*)(ws + 9699328);
  float* cb = (float*)(ws + 9961472);                  // 4 KB slot
  float* logits = (float*)(ws + 9965568);              // 512 KB
  float* wgt = (float*)(ws + 10489856);                // 512 KB
  float* spart = (float*)(ws + 11014144);              // 2 MB [128*8][512]
  float* Abuf = (float*)(ws + 13111296);               // 512 KB
  const size_t TE16_OFF = 14680064;                    // 14 MB
  const size_t TE16_BYTES = (size_t)128 * 1024 * 512 * 2;  // 128 MB
  unsigned short* te16 = (unsigned short*)(ws + TE16_OFF);
  const int use16 = (ws_size >= TE16_OFF + TE16_BYTES) ? 1 : 0;

  // weight transposes (coalesced mat-vec reads) + decoder W pre-pack
  transpose5_kernel<<<dim3(16, 16, 5), 256, 0, stream>>>(Wt1, Wt2, Wq, Wv, Wp,
                                                         Wt1T, Wt2T, WqT, WvT, WpT);
  transposed1_kernel<<<dim3(16, 32), 256, 0, stream>>>(Wd1, Wd1aT);
  convw_kernel<<<256, 256, 0, stream>>>(Wd1, wsW);

  // cond / q / qk chain (batched mat-vecs)
  gvec_kernel<0, 1><<<dim3(128, 2), 256, 0, stream>>>(Wt1T, 512, nullptr, nullptr, bt1, tsteps, hbuf);
  gvec_kernel<1, 0><<<dim3(128, 2), 256, 0, stream>>>(Wt2T, 512, hbuf, nullptr, bt2, nullptr, cond);
  gvec_kernel<2, 0><<<dim3(128, 2), 256, 0, stream>>>(WqT, 512, qe, cond, nullptr, nullptr, qbuf);
  gvec_kernel<1, 0><<<dim3(128, 2), 256, 0, stream>>>(Wk, 512, qbuf, nullptr, nullptr, nullptr, qk);
  dotk_kernel<<<128, 256, 0, stream>>>(qk, cond, cb);

  logits_kernel<<<32768, 256, 0, stream>>>(te, qk, cb, x, logits, te16, use16);
  softmax_kernel<<<128, 256, 0, stream>>>(logits, bd2, wgt, out);
  if (use16)
    wsum16_kernel<<<1024, 256, 0, stream>>>(te16, wgt, spart);
  else
    wsum32_kernel<<<1024, 256, 0, stream>>>(te, wgt, spart);

  // new_emb -> A chain
  gvec_kernel<3, 0><<<dim3(128, 2), 256, 0, stream>>>(WvT, 512, spart, cond, nullptr, nullptr, ubuf);
  gvec_kernel<1, 0><<<dim3(128, 2), 256, 0, stream>>>(WpT, 512, ubuf, nullptr, bp, nullptr, nebuf);
  gvec_kernel<1, 0><<<dim3(128, 4), 256, 0, stream>>>(Wd1aT, 1024, nebuf, nullptr, bd1, nullptr, Abuf);

  if (use16) {
    (void)hipFuncSetAttribute((const void*)decoder_kernel<1>,
                              hipFuncAttributeMaxDynamicSharedMemorySize, 65536);
    decoder_kernel<1><<<2048, 512, 65536, stream>>>(te, te16, wsW, Abuf, Wd2, out);
  } else {
    (void)hipFuncSetAttribute((const void*)decoder_kernel<0>,
                              hipFuncAttributeMaxDynamicSharedMemorySize, 65536);
    decoder_kernel<0><<<2048, 512, 65536, stream>>>(te, te16, wsW, Abuf, Wd2, out);
  }
}